// Round 9
// baseline (407.371 us; speedup 1.0000x reference)
//
#include <hip/hip_runtime.h>
#include <hip/hip_bf16.h>

#define N_NODES 100000
#define N_EDGES 1600000
#define NBUCK 391          // ceil(N_NODES / 256)
#define NBLK 256           // bucket-phase blocks
#define CHUNK (N_EDGES / NBLK)   // 6250, exact
#define MATP (NBUCK * NBLK)      // 100096, per-part count-matrix size

typedef __bf16 bf16x8 __attribute__((ext_vector_type(8)));
typedef float f32x4 __attribute__((ext_vector_type(4)));
typedef unsigned short u16x8 __attribute__((ext_vector_type(8)));
typedef _Float16 f16x8 __attribute__((ext_vector_type(8)));

// ---------------- helpers: f32 -> bf16 (RNE) split ----------------
__device__ __forceinline__ unsigned short f32_to_bf16_rne(float x) {
    unsigned int u = __float_as_uint(x);
    unsigned int r = u + 0x7FFFu + ((u >> 16) & 1u);
    return (unsigned short)(r >> 16);
}
__device__ __forceinline__ float bf16_bits_to_f32(unsigned short h) {
    return __uint_as_float(((unsigned int)h) << 16);
}

__device__ __forceinline__ void wtsplit_elem(const float* __restrict__ W,
                                             unsigned short* __restrict__ WTh,
                                             unsigned short* __restrict__ WTl,
                                             int K, int i) {
    int col = i / K, k = i - col * K;
    float x = W[(size_t)k * 128 + col];
    unsigned short h = f32_to_bf16_rne(x);
    unsigned short l = f32_to_bf16_rne(x - bf16_bits_to_f32(h));
    WTh[i] = h;
    WTl[i] = l;
}

// ---------------- fused setup: bucket histograms + weight transpose/split --
__global__ __launch_bounds__(256) void fused_setup(
    const int* __restrict__ esrc, const int* __restrict__ edst,
    int* __restrict__ cnt_mat,
    const float* __restrict__ W1, unsigned short* __restrict__ WT1h,
    unsigned short* __restrict__ WT1l,
    const float* __restrict__ W2, unsigned short* __restrict__ WT2h,
    unsigned short* __restrict__ WT2l)
{
    __shared__ int hd[NBUCK], hs[NBUCK];
    const int b = blockIdx.x, t = threadIdx.x;
    if (b < NBLK) {
        for (int i = t; i < NBUCK; i += 256) { hd[i] = 0; hs[i] = 0; }
        __syncthreads();
        const int e1 = (b + 1) * CHUNK;
        for (int e = b * CHUNK + t; e < e1; e += 256) {
            atomicAdd(&hd[edst[e] >> 8], 1);
            atomicAdd(&hs[esrc[e] >> 8], 1);
        }
        __syncthreads();
        for (int i = t; i < NBUCK; i += 256) {
            cnt_mat[i * NBLK + b] = hd[i];
            cnt_mat[MATP + i * NBLK + b] = hs[i];
        }
    } else {
        int i = (b - NBLK) * 256 + t;         // 0..49151
        if (i < 128 * 256) {
            wtsplit_elem(W1, WT1h, WT1l, 256, i);
        } else {
            int j = i - 128 * 256;            // < 16384
            wtsplit_elem(W2, WT2h, WT2l, 128, j);
        }
    }
}

// ---------------- flat exclusive scan (partials applied inline) ----------
__global__ __launch_bounds__(1024) void scan_blocks(const int* __restrict__ counts,
                                                    int* __restrict__ out,
                                                    int* __restrict__ partials, int n) {
    __shared__ int tmp[1024];
    int i = blockIdx.x * 1024 + threadIdx.x;
    int v = (i < n) ? counts[i] : 0;
    tmp[threadIdx.x] = v;
    __syncthreads();
    for (int off = 1; off < 1024; off <<= 1) {
        int t = (threadIdx.x >= (unsigned)off) ? tmp[threadIdx.x - off] : 0;
        __syncthreads();
        tmp[threadIdx.x] += t;
        __syncthreads();
    }
    if (i < n) out[i] = tmp[threadIdx.x] - v;
    if (threadIdx.x == 1023) partials[blockIdx.x] = tmp[1023];
}

__global__ void scan_partials(int* __restrict__ partials, int nb) {
    if (threadIdx.x == 0 && blockIdx.x == 0) {
        int s = 0;
        for (int b = 0; b < nb; ++b) { int t = partials[b]; partials[b] = s; s += t; }
    }
}

__device__ __forceinline__ int sm_at(const int* __restrict__ scan_mat,
                                     const int* __restrict__ partials, int i) {
    return scan_mat[i] + partials[i >> 10];
}

// ---------------- phase 2: scatter edges into bucket-sorted streams ------
__global__ __launch_bounds__(256) void bucket_scatter(const int* __restrict__ esrc,
                                                      const int* __restrict__ edst,
                                                      const int* __restrict__ scan_mat,
                                                      const int* __restrict__ partials,
                                                      unsigned int* __restrict__ tmp) {
    __shared__ int cd[NBUCK], cs[NBUCK];
    const int b = blockIdx.x, t = threadIdx.x;
    for (int i = t; i < NBUCK; i += 256) {
        cd[i] = sm_at(scan_mat, partials, i * NBLK + b);
        cs[i] = sm_at(scan_mat, partials, MATP + i * NBLK + b);
    }
    __syncthreads();
    const int e1 = (b + 1) * CHUNK;
    for (int e = b * CHUNK + t; e < e1; e += 256) {
        int s = esrc[e], d = edst[e];
        int pd = atomicAdd(&cd[d >> 8], 1);
        tmp[pd] = ((unsigned int)(d & 255) << 17) | (unsigned int)s;
        int ps = atomicAdd(&cs[s >> 8], 1);
        tmp[ps] = (unsigned int)s;
    }
}

// ---------------- phase 3: fused per-bucket finalize (dst + src) ---------
__global__ __launch_bounds__(256) void finalize_fused(
    const unsigned int* __restrict__ tmp,
    const int* __restrict__ scan_mat,
    const int* __restrict__ partials,
    int* __restrict__ rowptr,
    int* __restrict__ csr_src,
    float* __restrict__ ndst,
    float* __restrict__ nsrc)
{
    __shared__ int hist[256];
    __shared__ int scn[256];
    __shared__ int cur[256];
    const int bb = blockIdx.x, t = threadIdx.x;
    if (bb < NBUCK) {
        const int b = bb;
        const int beg = sm_at(scan_mat, partials, b * 256);
        const int end = sm_at(scan_mat, partials, (b + 1) * 256);
        hist[t] = 0;
        __syncthreads();
        for (int j = beg + t; j < end; j += 256)
            atomicAdd(&hist[tmp[j] >> 17], 1);
        __syncthreads();
        int v = hist[t];
        scn[t] = v;
        __syncthreads();
        for (int off = 1; off < 256; off <<= 1) {
            int u = (t >= off) ? scn[t - off] : 0;
            __syncthreads();
            scn[t] += u;
            __syncthreads();
        }
        int excl = scn[t] - v;
        int node = b * 256 + t;
        if (node <= N_NODES) rowptr[node] = beg + excl;
        if (node < N_NODES) ndst[node] = rsqrtf(fmaxf((float)v, 1.0f));
        cur[t] = beg + excl;
        __syncthreads();
        for (int j = beg + t; j < end; j += 256) {
            unsigned int x = tmp[j];
            int pos = atomicAdd(&cur[x >> 17], 1);
            csr_src[pos] = (int)(x & 0x1FFFFu);
        }
    } else {
        const int b = bb - NBUCK;
        const int beg = sm_at(scan_mat, partials, MATP + b * 256);
        const int end = (b < NBUCK - 1) ? sm_at(scan_mat, partials, MATP + (b + 1) * 256)
                                        : 2 * N_EDGES;
        hist[t] = 0;
        __syncthreads();
        for (int j = beg + t; j < end; j += 256)
            atomicAdd(&hist[tmp[j] & 255u], 1);
        __syncthreads();
        int node = b * 256 + t;
        if (node < N_NODES) nsrc[node] = rsqrtf(fmaxf((float)hist[t], 1.0f));
    }
}

// ---------------- LDS-free streaming MFMA GEMM (bf16 3-term split) --------
// Wave tile 32 rows x 128 cols; block = 4 waves (128 rows); no LDS, no barriers.
// A: f32 from global -> regs -> hi/lo bf16 split.  B: WT hi/lo from global (L1-hot).
// Output h16 in SLICE-MAJOR layout: h16[slice][row][c] , slice = col>>4 (= nt).
template<int K>
__global__ __launch_bounds__(256) void gemm_stream(
    const float* __restrict__ A,            // [M, K] f32
    const unsigned short* __restrict__ WTh, // [128][K] bf16 hi
    const unsigned short* __restrict__ WTl, // [128][K] bf16 lo
    const float* __restrict__ rowscale,     // [M]
    _Float16* __restrict__ C16,             // [8][M][16] f16 slice-major
    int M)
{
    const int tid = threadIdx.x;
    const int wid = tid >> 6;
    const int lane = tid & 63;
    const int lr = lane & 15;
    const int lg = lane >> 4;
    const int row0 = blockIdx.x * 128 + wid * 32;

    f32x4 acc[2][8];
    #pragma unroll
    for (int i = 0; i < 2; ++i)
        #pragma unroll
        for (int j = 0; j < 8; ++j)
            acc[i][j] = (f32x4){0.f, 0.f, 0.f, 0.f};

    // per-lane A rows (clamped to stay in-bounds; results discarded at store)
    int ra[2];
    {
        int r0 = row0 + lr;       ra[0] = (r0 < M) ? r0 : (M - 1);
        int r1 = row0 + 16 + lr;  ra[1] = (r1 < M) ? r1 : (M - 1);
    }

    for (int k0 = 0; k0 < K; k0 += 32) {
        // ---- A fragments: load f32x8, split to hi/lo bf16 ----
        bf16x8 ah[2], al[2];
        #pragma unroll
        for (int mt = 0; mt < 2; ++mt) {
            const float* ap = &A[(size_t)ra[mt] * K + k0 + lg * 8];
            float4 v0 = *reinterpret_cast<const float4*>(ap);
            float4 v1 = *reinterpret_cast<const float4*>(ap + 4);
            float v[8] = {v0.x, v0.y, v0.z, v0.w, v1.x, v1.y, v1.z, v1.w};
            union { u16x8 u; bf16x8 b; } ch, cl;
            #pragma unroll
            for (int j = 0; j < 8; ++j) {
                unsigned short h = f32_to_bf16_rne(v[j]);
                ch.u[j] = h;
                cl.u[j] = f32_to_bf16_rne(v[j] - bf16_bits_to_f32(h));
            }
            ah[mt] = ch.b;
            al[mt] = cl.b;
        }
        // ---- B fragments in 2 groups of 4 cols-of-16 (keeps regs low) ----
        #pragma unroll
        for (int ng = 0; ng < 2; ++ng) {
            bf16x8 bh[4], bl[4];
            #pragma unroll
            for (int i = 0; i < 4; ++i) {
                int col = (ng * 4 + i) * 16 + lr;
                const size_t g = (size_t)col * K + k0 + lg * 8;
                union { u16x8 u; bf16x8 b; } th, tl;
                th.u = *reinterpret_cast<const u16x8*>(&WTh[g]);
                tl.u = *reinterpret_cast<const u16x8*>(&WTl[g]);
                bh[i] = th.b;
                bl[i] = tl.b;
            }
            #pragma unroll
            for (int mt = 0; mt < 2; ++mt) {
                #pragma unroll
                for (int i = 0; i < 4; ++i) {
                    int nt = ng * 4 + i;
                    acc[mt][nt] = __builtin_amdgcn_mfma_f32_16x16x32_bf16(
                        ah[mt], bh[i], acc[mt][nt], 0, 0, 0);
                    acc[mt][nt] = __builtin_amdgcn_mfma_f32_16x16x32_bf16(
                        ah[mt], bl[i], acc[mt][nt], 0, 0, 0);
                    acc[mt][nt] = __builtin_amdgcn_mfma_f32_16x16x32_bf16(
                        al[mt], bh[i], acc[mt][nt], 0, 0, 0);
                }
            }
        }
    }

    // ---- epilogue: rowscale, store f16 slice-major ----
    const size_t N16 = (size_t)M * 16;
    #pragma unroll
    for (int mt = 0; mt < 2; ++mt) {
        #pragma unroll
        for (int r = 0; r < 4; ++r) {
            int row = row0 + mt * 16 + lg * 4 + r;
            if (row < M) {
                float s = rowscale[row];
                #pragma unroll
                for (int nt = 0; nt < 8; ++nt) {
                    C16[(size_t)nt * N16 + (size_t)row * 16 + lr] =
                        (_Float16)(acc[mt][nt][r] * s);
                }
            }
        }
    }
}

// ---------------- XCD-sliced CSR aggregation, fused epilogue -------------
// h16 is [8][N][16] slice-major. slice = blockIdx % 8 -> rides round-robin
// block->XCD dispatch so each XCD's gathers stay in its 3.2 MB L2-resident slice.
// 2 lanes per node (8 cols each), 128 nodes per 256-thread block.
__global__ __launch_bounds__(256) void aggregate_sliced(
    const _Float16* __restrict__ h16,
    const int* __restrict__ rowptr,
    const int* __restrict__ csr_src,
    const float* __restrict__ ndst,
    const float* __restrict__ bias,
    float* __restrict__ out, int N)
{
    const int b = blockIdx.x;
    const int slice = b & 7;
    const int nb = b >> 3;
    const int t = threadIdx.x;
    const int node = nb * 128 + (t >> 1);
    if (node >= N) return;
    const int p = t & 1;
    const _Float16* hs = h16 + (size_t)slice * ((size_t)N * 16) + p * 8;
    const int cg = slice * 16 + p * 8;   // global col base

    int beg = rowptr[node];
    int end = rowptr[node + 1];
    float acc[8] = {0.f, 0.f, 0.f, 0.f, 0.f, 0.f, 0.f, 0.f};
    int j = beg;
    for (; j + 3 < end; j += 4) {
        int s0 = csr_src[j];
        int s1 = csr_src[j + 1];
        int s2 = csr_src[j + 2];
        int s3 = csr_src[j + 3];
        f16x8 v0 = *reinterpret_cast<const f16x8*>(&hs[(size_t)s0 * 16]);
        f16x8 v1 = *reinterpret_cast<const f16x8*>(&hs[(size_t)s1 * 16]);
        f16x8 v2 = *reinterpret_cast<const f16x8*>(&hs[(size_t)s2 * 16]);
        f16x8 v3 = *reinterpret_cast<const f16x8*>(&hs[(size_t)s3 * 16]);
        #pragma unroll
        for (int k = 0; k < 8; ++k)
            acc[k] += ((float)v0[k] + (float)v1[k]) + ((float)v2[k] + (float)v3[k]);
    }
    for (; j < end; ++j) {
        int s0 = csr_src[j];
        f16x8 v0 = *reinterpret_cast<const f16x8*>(&hs[(size_t)s0 * 16]);
        #pragma unroll
        for (int k = 0; k < 8; ++k) acc[k] += (float)v0[k];
    }
    float sc = ndst[node];
    const float4 b0 = *reinterpret_cast<const float4*>(&bias[cg]);
    const float4 b1 = *reinterpret_cast<const float4*>(&bias[cg + 4]);
    float4 r0, r1;
    r0.x = fmaxf(acc[0] * sc + b0.x, 0.f);
    r0.y = fmaxf(acc[1] * sc + b0.y, 0.f);
    r0.z = fmaxf(acc[2] * sc + b0.z, 0.f);
    r0.w = fmaxf(acc[3] * sc + b0.w, 0.f);
    r1.x = fmaxf(acc[4] * sc + b1.x, 0.f);
    r1.y = fmaxf(acc[5] * sc + b1.y, 0.f);
    r1.z = fmaxf(acc[6] * sc + b1.z, 0.f);
    r1.w = fmaxf(acc[7] * sc + b1.w, 0.f);
    float* op = &out[(size_t)node * 128 + cg];
    *reinterpret_cast<float4*>(op) = r0;
    *reinterpret_cast<float4*>(op + 4) = r1;
}

extern "C" void kernel_launch(void* const* d_in, const int* in_sizes, int n_in,
                              void* d_out, int out_size, void* d_ws, size_t ws_size,
                              hipStream_t stream) {
    const float* feat = (const float*)d_in[0];   // [1, N, 256]
    const float* W1   = (const float*)d_in[1];   // [256, 128]
    const float* b1   = (const float*)d_in[2];   // [128]
    const float* W2   = (const float*)d_in[3];   // [128, 128]
    const float* b2   = (const float*)d_in[4];   // [128]
    const int* esrc   = (const int*)d_in[5];     // [E]
    const int* edst   = (const int*)d_in[6];     // [E]
    float* out = (float*)d_out;                  // [N, 128]

    const int Nn = N_NODES, E = N_EDGES;
    const int SCAN_N = 2 * MATP;                 // 200192
    const int SCAN_NB = (SCAN_N + 1023) / 1024;  // 196

    float* hseg   = (float*)d_ws;
    _Float16* h16 = (_Float16*)hseg;             // [8][N][16] slice-major
    unsigned short* WT1h = (unsigned short*)(hseg + (size_t)Nn * 128);
    unsigned short* WT1l = WT1h + 128 * 256;
    unsigned short* WT2h = WT1l + 128 * 256;
    unsigned short* WT2l = WT2h + 128 * 128;
    int* csr_src  = (int*)(WT2l + 128 * 128);
    int* rowptr   = csr_src + E;
    unsigned int* tmp = (unsigned int*)(rowptr + 100004);
    int* cnt_mat  = (int*)(tmp + 2 * (size_t)E);
    int* scan_mat = cnt_mat + SCAN_N;
    int* partials = scan_mat + SCAN_N;
    float* nsrc   = (float*)(partials + ((SCAN_NB + 3) & ~3));
    float* ndst   = nsrc + Nn;

    // --- setup: bucket histograms + weight transpose/split (fused) ---
    fused_setup<<<NBLK + 192, 256, 0, stream>>>(esrc, edst, cnt_mat,
                                                W1, WT1h, WT1l, W2, WT2h, WT2l);

    // --- scan ---
    scan_blocks<<<SCAN_NB, 1024, 0, stream>>>(cnt_mat, scan_mat, partials, SCAN_N);
    scan_partials<<<1, 64, 0, stream>>>(partials, SCAN_NB);

    // --- scatter + fused finalize ---
    bucket_scatter<<<NBLK, 256, 0, stream>>>(esrc, edst, scan_mat, partials, tmp);
    finalize_fused<<<2 * NBUCK, 256, 0, stream>>>(tmp, scan_mat, partials,
                                                  rowptr, csr_src, ndst, nsrc);

    const int gemm_grid = (Nn + 127) / 128;          // 782
    const int agg_grid  = 8 * ((Nn + 127) / 128);    // 6256

    // --- layer 1 ---
    gemm_stream<256><<<gemm_grid, 256, 0, stream>>>(feat, WT1h, WT1l, nsrc, h16, Nn);
    aggregate_sliced<<<agg_grid, 256, 0, stream>>>(h16, rowptr, csr_src, ndst, b1, out, Nn);

    // --- layer 2 ---
    gemm_stream<128><<<gemm_grid, 256, 0, stream>>>(out, WT2h, WT2l, nsrc, h16, Nn);
    aggregate_sliced<<<agg_grid, 256, 0, stream>>>(h16, rowptr, csr_src, ndst, b2, out, Nn);
}

// Round 10
// 267.124 us; speedup vs baseline: 1.5250x; 1.5250x over previous
//
#include <hip/hip_runtime.h>
#include <hip/hip_bf16.h>

#define N_NODES 100000
#define N_EDGES 1600000
#define NBUCK 391          // ceil(N_NODES / 256)
#define NBLK 256           // bucket-phase blocks
#define CHUNK (N_EDGES / NBLK)   // 6250, exact
#define MATP (NBUCK * NBLK)      // 100096, per-part count-matrix size

typedef __bf16 bf16x8 __attribute__((ext_vector_type(8)));
typedef float f32x4 __attribute__((ext_vector_type(4)));
typedef unsigned short u16x8 __attribute__((ext_vector_type(8)));
typedef _Float16 f16x8 __attribute__((ext_vector_type(8)));

// ---------------- helpers: f32 -> bf16 (RNE) split ----------------
__device__ __forceinline__ unsigned short f32_to_bf16_rne(float x) {
    unsigned int u = __float_as_uint(x);
    unsigned int r = u + 0x7FFFu + ((u >> 16) & 1u);
    return (unsigned short)(r >> 16);
}
__device__ __forceinline__ float bf16_bits_to_f32(unsigned short h) {
    return __uint_as_float(((unsigned int)h) << 16);
}

__device__ __forceinline__ void wtsplit_elem(const float* __restrict__ W,
                                             unsigned short* __restrict__ WTh,
                                             unsigned short* __restrict__ WTl,
                                             int K, int i) {
    int col = i / K, k = i - col * K;
    float x = W[(size_t)k * 128 + col];
    unsigned short h = f32_to_bf16_rne(x);
    unsigned short l = f32_to_bf16_rne(x - bf16_bits_to_f32(h));
    WTh[i] = h;
    WTl[i] = l;
}

// ---------------- fused setup: bucket histograms + weight transpose/split --
__global__ __launch_bounds__(256) void fused_setup(
    const int* __restrict__ esrc, const int* __restrict__ edst,
    int* __restrict__ cnt_mat,
    const float* __restrict__ W1, unsigned short* __restrict__ WT1h,
    unsigned short* __restrict__ WT1l,
    const float* __restrict__ W2, unsigned short* __restrict__ WT2h,
    unsigned short* __restrict__ WT2l)
{
    __shared__ int hd[NBUCK], hs[NBUCK];
    const int b = blockIdx.x, t = threadIdx.x;
    if (b < NBLK) {
        for (int i = t; i < NBUCK; i += 256) { hd[i] = 0; hs[i] = 0; }
        __syncthreads();
        const int e1 = (b + 1) * CHUNK;
        for (int e = b * CHUNK + t; e < e1; e += 256) {
            atomicAdd(&hd[edst[e] >> 8], 1);
            atomicAdd(&hs[esrc[e] >> 8], 1);
        }
        __syncthreads();
        for (int i = t; i < NBUCK; i += 256) {
            cnt_mat[i * NBLK + b] = hd[i];
            cnt_mat[MATP + i * NBLK + b] = hs[i];
        }
    } else {
        int i = (b - NBLK) * 256 + t;         // 0..49151
        if (i < 128 * 256) {
            wtsplit_elem(W1, WT1h, WT1l, 256, i);
        } else {
            int j = i - 128 * 256;            // < 16384
            wtsplit_elem(W2, WT2h, WT2l, 128, j);
        }
    }
}

// ---------------- flat exclusive scan (partials applied inline) ----------
__global__ __launch_bounds__(1024) void scan_blocks(const int* __restrict__ counts,
                                                    int* __restrict__ out,
                                                    int* __restrict__ partials, int n) {
    __shared__ int tmp[1024];
    int i = blockIdx.x * 1024 + threadIdx.x;
    int v = (i < n) ? counts[i] : 0;
    tmp[threadIdx.x] = v;
    __syncthreads();
    for (int off = 1; off < 1024; off <<= 1) {
        int t = (threadIdx.x >= (unsigned)off) ? tmp[threadIdx.x - off] : 0;
        __syncthreads();
        tmp[threadIdx.x] += t;
        __syncthreads();
    }
    if (i < n) out[i] = tmp[threadIdx.x] - v;
    if (threadIdx.x == 1023) partials[blockIdx.x] = tmp[1023];
}

__global__ void scan_partials(int* __restrict__ partials, int nb) {
    if (threadIdx.x == 0 && blockIdx.x == 0) {
        int s = 0;
        for (int b = 0; b < nb; ++b) { int t = partials[b]; partials[b] = s; s += t; }
    }
}

__device__ __forceinline__ int sm_at(const int* __restrict__ scan_mat,
                                     const int* __restrict__ partials, int i) {
    return scan_mat[i] + partials[i >> 10];
}

// ---------------- phase 2: scatter edges into bucket-sorted streams ------
__global__ __launch_bounds__(256) void bucket_scatter(const int* __restrict__ esrc,
                                                      const int* __restrict__ edst,
                                                      const int* __restrict__ scan_mat,
                                                      const int* __restrict__ partials,
                                                      unsigned int* __restrict__ tmp) {
    __shared__ int cd[NBUCK], cs[NBUCK];
    const int b = blockIdx.x, t = threadIdx.x;
    for (int i = t; i < NBUCK; i += 256) {
        cd[i] = sm_at(scan_mat, partials, i * NBLK + b);
        cs[i] = sm_at(scan_mat, partials, MATP + i * NBLK + b);
    }
    __syncthreads();
    const int e1 = (b + 1) * CHUNK;
    for (int e = b * CHUNK + t; e < e1; e += 256) {
        int s = esrc[e], d = edst[e];
        int pd = atomicAdd(&cd[d >> 8], 1);
        tmp[pd] = ((unsigned int)(d & 255) << 17) | (unsigned int)s;
        int ps = atomicAdd(&cs[s >> 8], 1);
        tmp[ps] = (unsigned int)s;
    }
}

// ---------------- phase 3: fused per-bucket finalize (dst + src) ---------
__global__ __launch_bounds__(256) void finalize_fused(
    const unsigned int* __restrict__ tmp,
    const int* __restrict__ scan_mat,
    const int* __restrict__ partials,
    int* __restrict__ rowptr,
    int* __restrict__ csr_src,
    float* __restrict__ ndst,
    float* __restrict__ nsrc)
{
    __shared__ int hist[256];
    __shared__ int scn[256];
    __shared__ int cur[256];
    const int bb = blockIdx.x, t = threadIdx.x;
    if (bb < NBUCK) {
        const int b = bb;
        const int beg = sm_at(scan_mat, partials, b * 256);
        const int end = sm_at(scan_mat, partials, (b + 1) * 256);
        hist[t] = 0;
        __syncthreads();
        for (int j = beg + t; j < end; j += 256)
            atomicAdd(&hist[tmp[j] >> 17], 1);
        __syncthreads();
        int v = hist[t];
        scn[t] = v;
        __syncthreads();
        for (int off = 1; off < 256; off <<= 1) {
            int u = (t >= off) ? scn[t - off] : 0;
            __syncthreads();
            scn[t] += u;
            __syncthreads();
        }
        int excl = scn[t] - v;
        int node = b * 256 + t;
        if (node <= N_NODES) rowptr[node] = beg + excl;
        if (node < N_NODES) ndst[node] = rsqrtf(fmaxf((float)v, 1.0f));
        cur[t] = beg + excl;
        __syncthreads();
        for (int j = beg + t; j < end; j += 256) {
            unsigned int x = tmp[j];
            int pos = atomicAdd(&cur[x >> 17], 1);
            csr_src[pos] = (int)(x & 0x1FFFFu);
        }
    } else {
        const int b = bb - NBUCK;
        const int beg = sm_at(scan_mat, partials, MATP + b * 256);
        const int end = (b < NBUCK - 1) ? sm_at(scan_mat, partials, MATP + (b + 1) * 256)
                                        : 2 * N_EDGES;
        hist[t] = 0;
        __syncthreads();
        for (int j = beg + t; j < end; j += 256)
            atomicAdd(&hist[tmp[j] & 255u], 1);
        __syncthreads();
        int node = b * 256 + t;
        if (node < N_NODES) nsrc[node] = rsqrtf(fmaxf((float)hist[t], 1.0f));
    }
}

// ---------------- MFMA GEMM (bf16 3-term split), f16 output --------------
// BM=64, BN=128, BK=32; 4 waves (2x2).
// LDS layout: slot-major [slot][row][8] with slot stride ≡ 4 (mod 32) dword
// banks (A: 520 u16 = 1040 B, B: 1032 u16 = 2064 B) -> reads exact 2-way
// (free), writes uniform-minimal. Register prefetch of next K-tile.
template<int K, typename AT>
__global__ __launch_bounds__(256) void gemm_mfma(
    const AT* __restrict__ A,               // [M, K] f32 or f16
    const unsigned short* __restrict__ WTh, // [128][K] bf16 hi
    const unsigned short* __restrict__ WTl, // [128][K] bf16 lo
    const float* __restrict__ rowscale,     // [M]
    _Float16* __restrict__ C16,             // [M, 128] f16 out
    int M)
{
    constexpr int ASTR = 520;   // slot stride (ushorts) for A: 64*8 + 8
    constexpr int BSTR = 1032;  // slot stride (ushorts) for B: 128*8 + 8
    __shared__ unsigned short Ah[4 * ASTR];
    __shared__ unsigned short Al[4 * ASTR];
    __shared__ unsigned short Bh[4 * BSTR];
    __shared__ unsigned short Bl[4 * BSTR];

    const int tid = threadIdx.x;
    const int bm = blockIdx.x * 64;
    const int lane = tid & 63;
    const int wid = tid >> 6;
    const int wm = wid >> 1;         // 0..1: 32-row half
    const int wn = wid & 1;          // 0..1: 64-col half
    const int lr = lane & 15;
    const int lg = lane >> 4;

    const int st_ar = tid >> 2;      // A staging row 0..63
    const int st_s8 = tid & 3;       // A staging k-slot
    const int a_row_g = bm + st_ar;

    f32x4 acc[2][4];
    #pragma unroll
    for (int i = 0; i < 2; ++i)
        #pragma unroll
        for (int j = 0; j < 4; ++j)
            acc[i][j] = (f32x4){0.f, 0.f, 0.f, 0.f};

    float avreg[8];
    u16x8 bvh[2], bvl[2];

    auto load_tile = [&](int k0) {
        if (a_row_g < M) {
            const AT* ap = &A[(size_t)a_row_g * K + k0 + st_s8 * 8];
            if constexpr (sizeof(AT) == 4) {
                float4 v0 = *reinterpret_cast<const float4*>(ap);
                float4 v1 = *reinterpret_cast<const float4*>(ap + 4);
                avreg[0] = v0.x; avreg[1] = v0.y; avreg[2] = v0.z; avreg[3] = v0.w;
                avreg[4] = v1.x; avreg[5] = v1.y; avreg[6] = v1.z; avreg[7] = v1.w;
            } else {
                f16x8 v = *reinterpret_cast<const f16x8*>(ap);
                #pragma unroll
                for (int j = 0; j < 8; ++j) avreg[j] = (float)v[j];
            }
        } else {
            #pragma unroll
            for (int j = 0; j < 8; ++j) avreg[j] = 0.f;
        }
        #pragma unroll
        for (int i = 0; i < 2; ++i) {
            int lin = tid + i * 256;
            int col = lin >> 2;
            int s8  = lin & 3;
            const size_t g = (size_t)col * K + k0 + s8 * 8;
            bvh[i] = *reinterpret_cast<const u16x8*>(&WTh[g]);
            bvl[i] = *reinterpret_cast<const u16x8*>(&WTl[g]);
        }
    };

    load_tile(0);

    for (int k0 = 0; k0 < K; k0 += 32) {
        // ---- convert + write LDS from regs ----
        {
            u16x8 vh, vl;
            #pragma unroll
            for (int j = 0; j < 8; ++j) {
                unsigned short h = f32_to_bf16_rne(avreg[j]);
                vh[j] = h;
                vl[j] = f32_to_bf16_rne(avreg[j] - bf16_bits_to_f32(h));
            }
            int off = st_s8 * ASTR + st_ar * 8;
            *reinterpret_cast<u16x8*>(&Ah[off]) = vh;
            *reinterpret_cast<u16x8*>(&Al[off]) = vl;
            #pragma unroll
            for (int i = 0; i < 2; ++i) {
                int lin = tid + i * 256;
                int col = lin >> 2;
                int s8  = lin & 3;
                int boff = s8 * BSTR + col * 8;
                *reinterpret_cast<u16x8*>(&Bh[boff]) = bvh[i];
                *reinterpret_cast<u16x8*>(&Bl[boff]) = bvl[i];
            }
        }
        __syncthreads();

        if (k0 + 32 < K) load_tile(k0 + 32);

        // ---- MFMA: one K=32 substep ----
        {
            bf16x8 afh[2], afl[2], bfh[4], bfl[4];
            #pragma unroll
            for (int mt = 0; mt < 2; ++mt) {
                int row = wm * 32 + mt * 16 + lr;
                int off = lg * ASTR + row * 8;
                afh[mt] = *reinterpret_cast<const bf16x8*>(&Ah[off]);
                afl[mt] = *reinterpret_cast<const bf16x8*>(&Al[off]);
            }
            #pragma unroll
            for (int nt = 0; nt < 4; ++nt) {
                int col = wn * 64 + nt * 16 + lr;
                int off = lg * BSTR + col * 8;
                bfh[nt] = *reinterpret_cast<const bf16x8*>(&Bh[off]);
                bfl[nt] = *reinterpret_cast<const bf16x8*>(&Bl[off]);
            }
            #pragma unroll
            for (int mt = 0; mt < 2; ++mt) {
                #pragma unroll
                for (int nt = 0; nt < 4; ++nt) {
                    acc[mt][nt] = __builtin_amdgcn_mfma_f32_16x16x32_bf16(
                        afh[mt], bfh[nt], acc[mt][nt], 0, 0, 0);
                    acc[mt][nt] = __builtin_amdgcn_mfma_f32_16x16x32_bf16(
                        afh[mt], bfl[nt], acc[mt][nt], 0, 0, 0);
                    acc[mt][nt] = __builtin_amdgcn_mfma_f32_16x16x32_bf16(
                        afl[mt], bfh[nt], acc[mt][nt], 0, 0, 0);
                }
            }
        }
        __syncthreads();
    }

    #pragma unroll
    for (int mt = 0; mt < 2; ++mt) {
        #pragma unroll
        for (int r = 0; r < 4; ++r) {
            int row = bm + wm * 32 + mt * 16 + lg * 4 + r;
            if (row < M) {
                float s = rowscale[row];
                #pragma unroll
                for (int nt = 0; nt < 4; ++nt) {
                    int col = wn * 64 + nt * 16 + lr;
                    C16[(size_t)row * 128 + col] = (_Float16)(acc[mt][nt][r] * s);
                }
            }
        }
    }
}

// ---------------- CSR aggregation, column-split half (64 cols/pass) ------
// 8 lanes per node, 8 cols each; 4-wide gather unroll. OT = f16 or f32 out.
template<typename OT>
__global__ __launch_bounds__(256) void aggregate_half(
    const _Float16* __restrict__ h16,
    const int* __restrict__ rowptr,
    const int* __restrict__ csr_src,
    const float* __restrict__ ndst,
    const float* __restrict__ bias,
    OT* __restrict__ out, int N, int c_base)
{
    int g = blockIdx.x * blockDim.x + threadIdx.x;
    int node = g >> 3;
    if (node >= N) return;
    int c8 = ((g & 7) * 8) + c_base;
    int beg = rowptr[node];
    int end = rowptr[node + 1];
    float acc[8] = {0.f, 0.f, 0.f, 0.f, 0.f, 0.f, 0.f, 0.f};
    int j = beg;
    for (; j + 3 < end; j += 4) {
        int s0 = csr_src[j];
        int s1 = csr_src[j + 1];
        int s2 = csr_src[j + 2];
        int s3 = csr_src[j + 3];
        f16x8 v0 = *reinterpret_cast<const f16x8*>(&h16[(size_t)s0 * 128 + c8]);
        f16x8 v1 = *reinterpret_cast<const f16x8*>(&h16[(size_t)s1 * 128 + c8]);
        f16x8 v2 = *reinterpret_cast<const f16x8*>(&h16[(size_t)s2 * 128 + c8]);
        f16x8 v3 = *reinterpret_cast<const f16x8*>(&h16[(size_t)s3 * 128 + c8]);
        #pragma unroll
        for (int k = 0; k < 8; ++k)
            acc[k] += ((float)v0[k] + (float)v1[k]) + ((float)v2[k] + (float)v3[k]);
    }
    for (; j < end; ++j) {
        int s0 = csr_src[j];
        f16x8 v0 = *reinterpret_cast<const f16x8*>(&h16[(size_t)s0 * 128 + c8]);
        #pragma unroll
        for (int k = 0; k < 8; ++k) acc[k] += (float)v0[k];
    }
    float sc = ndst[node];
    const float4 b0 = *reinterpret_cast<const float4*>(&bias[c8]);
    const float4 b1 = *reinterpret_cast<const float4*>(&bias[c8 + 4]);
    float r[8];
    r[0] = fmaxf(acc[0] * sc + b0.x, 0.f);
    r[1] = fmaxf(acc[1] * sc + b0.y, 0.f);
    r[2] = fmaxf(acc[2] * sc + b0.z, 0.f);
    r[3] = fmaxf(acc[3] * sc + b0.w, 0.f);
    r[4] = fmaxf(acc[4] * sc + b1.x, 0.f);
    r[5] = fmaxf(acc[5] * sc + b1.y, 0.f);
    r[6] = fmaxf(acc[6] * sc + b1.z, 0.f);
    r[7] = fmaxf(acc[7] * sc + b1.w, 0.f);
    OT* op = &out[(size_t)node * 128 + c8];
    if constexpr (sizeof(OT) == 4) {
        float4 r0 = {r[0], r[1], r[2], r[3]};
        float4 r1 = {r[4], r[5], r[6], r[7]};
        *reinterpret_cast<float4*>(op) = r0;
        *reinterpret_cast<float4*>(op + 4) = r1;
    } else {
        f16x8 rv;
        #pragma unroll
        for (int k = 0; k < 8; ++k) rv[k] = (_Float16)r[k];
        *reinterpret_cast<f16x8*>(op) = rv;
    }
}

extern "C" void kernel_launch(void* const* d_in, const int* in_sizes, int n_in,
                              void* d_out, int out_size, void* d_ws, size_t ws_size,
                              hipStream_t stream) {
    const float* feat = (const float*)d_in[0];   // [1, N, 256]
    const float* W1   = (const float*)d_in[1];   // [256, 128]
    const float* b1   = (const float*)d_in[2];   // [128]
    const float* W2   = (const float*)d_in[3];   // [128, 128]
    const float* b2   = (const float*)d_in[4];   // [128]
    const int* esrc   = (const int*)d_in[5];     // [E]
    const int* edst   = (const int*)d_in[6];     // [E]
    float* out = (float*)d_out;                  // [N, 128]

    const int Nn = N_NODES, E = N_EDGES;
    const int SCAN_N = 2 * MATP;                 // 200192
    const int SCAN_NB = (SCAN_N + 1023) / 1024;  // 196

    // workspace: h slot (N*128 f32-sized) holds TWO f16 buffers:
    //   h16   = gemm output [N][128] f16 (first half)
    //   h1out = layer-1 aggregate output [N][128] f16 (second half)
    float* hseg   = (float*)d_ws;
    _Float16* h16   = (_Float16*)hseg;
    _Float16* h1out = h16 + (size_t)Nn * 128;
    unsigned short* WT1h = (unsigned short*)(hseg + (size_t)Nn * 128);
    unsigned short* WT1l = WT1h + 128 * 256;
    unsigned short* WT2h = WT1l + 128 * 256;
    unsigned short* WT2l = WT2h + 128 * 128;
    int* csr_src  = (int*)(WT2l + 128 * 128);
    int* rowptr   = csr_src + E;
    unsigned int* tmp = (unsigned int*)(rowptr + 100004);
    int* cnt_mat  = (int*)(tmp + 2 * (size_t)E);
    int* scan_mat = cnt_mat + SCAN_N;
    int* partials = scan_mat + SCAN_N;
    float* nsrc   = (float*)(partials + ((SCAN_NB + 3) & ~3));
    float* ndst   = nsrc + Nn;

    // --- setup: bucket histograms + weight transpose/split (fused) ---
    fused_setup<<<NBLK + 192, 256, 0, stream>>>(esrc, edst, cnt_mat,
                                                W1, WT1h, WT1l, W2, WT2h, WT2l);

    // --- scan ---
    scan_blocks<<<SCAN_NB, 1024, 0, stream>>>(cnt_mat, scan_mat, partials, SCAN_N);
    scan_partials<<<1, 64, 0, stream>>>(partials, SCAN_NB);

    // --- scatter + fused finalize ---
    bucket_scatter<<<NBLK, 256, 0, stream>>>(esrc, edst, scan_mat, partials, tmp);
    finalize_fused<<<2 * NBUCK, 256, 0, stream>>>(tmp, scan_mat, partials,
                                                  rowptr, csr_src, ndst, nsrc);

    const int gemm_grid = (Nn + 63) / 64;        // 1563
    const int aggh_grid = (Nn * 8 + 255) / 256;  // 3125

    // --- layer 1: gemm -> h16; aggregate (2 col passes) -> h1out (f16) ---
    gemm_mfma<256, float><<<gemm_grid, 256, 0, stream>>>(feat, WT1h, WT1l, nsrc, h16, Nn);
    aggregate_half<_Float16><<<aggh_grid, 256, 0, stream>>>(h16, rowptr, csr_src, ndst, b1, h1out, Nn, 0);
    aggregate_half<_Float16><<<aggh_grid, 256, 0, stream>>>(h16, rowptr, csr_src, ndst, b1, h1out, Nn, 64);

    // --- layer 2: gemm (reads f16 h1out) -> h16; aggregate -> d_out (f32) ---
    gemm_mfma<128, _Float16><<<gemm_grid, 256, 0, stream>>>(h1out, WT2h, WT2l, nsrc, h16, Nn);
    aggregate_half<float><<<aggh_grid, 256, 0, stream>>>(h16, rowptr, csr_src, ndst, b2, out, Nn, 0);
    aggregate_half<float><<<aggh_grid, 256, 0, stream>>>(h16, rowptr, csr_src, ndst, b2, out, Nn, 64);
}

// Round 11
// 223.736 us; speedup vs baseline: 1.8208x; 1.1939x over previous
//
#include <hip/hip_runtime.h>
#include <hip/hip_bf16.h>

#define N_NODES 100000
#define N_EDGES 1600000
#define NBUCK 391          // ceil(N_NODES / 256)
#define NBLK 256           // bucket-phase blocks
#define CHUNK (N_EDGES / NBLK)   // 6250, exact
#define MATP (NBUCK * NBLK)      // 100096, per-part count-matrix size

typedef float f32x4 __attribute__((ext_vector_type(4)));
typedef unsigned short u16x8 __attribute__((ext_vector_type(8)));
typedef _Float16 f16x8 __attribute__((ext_vector_type(8)));

// ---------------- fused setup: bucket histograms + weight transpose (f16) --
__device__ __forceinline__ void wt_elem(const float* __restrict__ W,
                                        _Float16* __restrict__ WTf,
                                        int K, int i) {
    int col = i / K, k = i - col * K;
    WTf[i] = (_Float16)W[(size_t)k * 128 + col];
}

__global__ __launch_bounds__(256) void fused_setup(
    const int* __restrict__ esrc, const int* __restrict__ edst,
    int* __restrict__ cnt_mat,
    const float* __restrict__ W1, _Float16* __restrict__ WT1f,
    const float* __restrict__ W2, _Float16* __restrict__ WT2f)
{
    __shared__ int hd[NBUCK], hs[NBUCK];
    const int b = blockIdx.x, t = threadIdx.x;
    if (b < NBLK) {
        for (int i = t; i < NBUCK; i += 256) { hd[i] = 0; hs[i] = 0; }
        __syncthreads();
        const int e1 = (b + 1) * CHUNK;
        for (int e = b * CHUNK + t; e < e1; e += 256) {
            atomicAdd(&hd[edst[e] >> 8], 1);
            atomicAdd(&hs[esrc[e] >> 8], 1);
        }
        __syncthreads();
        for (int i = t; i < NBUCK; i += 256) {
            cnt_mat[i * NBLK + b] = hd[i];
            cnt_mat[MATP + i * NBLK + b] = hs[i];
        }
    } else {
        int i = (b - NBLK) * 256 + t;         // 0..49151
        if (i < 128 * 256) {
            wt_elem(W1, WT1f, 256, i);
        } else {
            int j = i - 128 * 256;            // < 16384
            wt_elem(W2, WT2f, 128, j);
        }
    }
}

// ---------------- flat exclusive scan (partials applied inline) ----------
__global__ __launch_bounds__(1024) void scan_blocks(const int* __restrict__ counts,
                                                    int* __restrict__ out,
                                                    int* __restrict__ partials, int n) {
    __shared__ int tmp[1024];
    int i = blockIdx.x * 1024 + threadIdx.x;
    int v = (i < n) ? counts[i] : 0;
    tmp[threadIdx.x] = v;
    __syncthreads();
    for (int off = 1; off < 1024; off <<= 1) {
        int t = (threadIdx.x >= (unsigned)off) ? tmp[threadIdx.x - off] : 0;
        __syncthreads();
        tmp[threadIdx.x] += t;
        __syncthreads();
    }
    if (i < n) out[i] = tmp[threadIdx.x] - v;
    if (threadIdx.x == 1023) partials[blockIdx.x] = tmp[1023];
}

// parallel one-block exclusive scan over nb (<256) partials
__global__ __launch_bounds__(256) void scan_partials(int* __restrict__ partials, int nb) {
    __shared__ int tmp[256];
    int t = threadIdx.x;
    int v = (t < nb) ? partials[t] : 0;
    tmp[t] = v;
    __syncthreads();
    for (int off = 1; off < 256; off <<= 1) {
        int u = (t >= off) ? tmp[t - off] : 0;
        __syncthreads();
        tmp[t] += u;
        __syncthreads();
    }
    if (t < nb) partials[t] = tmp[t] - v;  // exclusive
}

__device__ __forceinline__ int sm_at(const int* __restrict__ scan_mat,
                                     const int* __restrict__ partials, int i) {
    return scan_mat[i] + partials[i >> 10];
}

// ---------------- phase 2: scatter edges into bucket-sorted streams ------
__global__ __launch_bounds__(256) void bucket_scatter(const int* __restrict__ esrc,
                                                      const int* __restrict__ edst,
                                                      const int* __restrict__ scan_mat,
                                                      const int* __restrict__ partials,
                                                      unsigned int* __restrict__ tmp) {
    __shared__ int cd[NBUCK], cs[NBUCK];
    const int b = blockIdx.x, t = threadIdx.x;
    for (int i = t; i < NBUCK; i += 256) {
        cd[i] = sm_at(scan_mat, partials, i * NBLK + b);
        cs[i] = sm_at(scan_mat, partials, MATP + i * NBLK + b);
    }
    __syncthreads();
    const int e1 = (b + 1) * CHUNK;
    for (int e = b * CHUNK + t; e < e1; e += 256) {
        int s = esrc[e], d = edst[e];
        int pd = atomicAdd(&cd[d >> 8], 1);
        tmp[pd] = ((unsigned int)(d & 255) << 17) | (unsigned int)s;
        int ps = atomicAdd(&cs[s >> 8], 1);
        tmp[ps] = (unsigned int)s;
    }
}

// ---------------- phase 3: fused per-bucket finalize (dst + src) ---------
__global__ __launch_bounds__(256) void finalize_fused(
    const unsigned int* __restrict__ tmp,
    const int* __restrict__ scan_mat,
    const int* __restrict__ partials,
    int* __restrict__ rowptr,
    int* __restrict__ csr_src,
    float* __restrict__ ndst,
    float* __restrict__ nsrc)
{
    __shared__ int hist[256];
    __shared__ int scn[256];
    __shared__ int cur[256];
    const int bb = blockIdx.x, t = threadIdx.x;
    if (bb < NBUCK) {
        const int b = bb;
        const int beg = sm_at(scan_mat, partials, b * 256);
        const int end = sm_at(scan_mat, partials, (b + 1) * 256);
        hist[t] = 0;
        __syncthreads();
        for (int j = beg + t; j < end; j += 256)
            atomicAdd(&hist[tmp[j] >> 17], 1);
        __syncthreads();
        int v = hist[t];
        scn[t] = v;
        __syncthreads();
        for (int off = 1; off < 256; off <<= 1) {
            int u = (t >= off) ? scn[t - off] : 0;
            __syncthreads();
            scn[t] += u;
            __syncthreads();
        }
        int excl = scn[t] - v;
        int node = b * 256 + t;
        if (node <= N_NODES) rowptr[node] = beg + excl;
        if (node < N_NODES) ndst[node] = rsqrtf(fmaxf((float)v, 1.0f));
        cur[t] = beg + excl;
        __syncthreads();
        for (int j = beg + t; j < end; j += 256) {
            unsigned int x = tmp[j];
            int pos = atomicAdd(&cur[x >> 17], 1);
            csr_src[pos] = (int)(x & 0x1FFFFu);
        }
    } else {
        const int b = bb - NBUCK;
        const int beg = sm_at(scan_mat, partials, MATP + b * 256);
        const int end = (b < NBUCK - 1) ? sm_at(scan_mat, partials, MATP + (b + 1) * 256)
                                        : 2 * N_EDGES;
        hist[t] = 0;
        __syncthreads();
        for (int j = beg + t; j < end; j += 256)
            atomicAdd(&hist[tmp[j] & 255u], 1);
        __syncthreads();
        int node = b * 256 + t;
        if (node < N_NODES) nsrc[node] = rsqrtf(fmaxf((float)hist[t], 1.0f));
    }
}

// ---------------- MFMA GEMM, f16 operands, f32 accumulate ----------------
// BM=64, BN=128, BK=32; 4 waves (2x2).
// Layer 1 (AT=float, ATERMS=2): A = ah + al (two f16, exact to 2^-22); W = f16.
// Layer 2 (AT=f16, ATERMS=1): A exact f16, single term.
// LDS slot-major [slot][row/col][8], slot strides ≡ 4 (mod 32) dword banks.
template<int K, int ATERMS, typename AT>
__global__ __launch_bounds__(256) void gemm_mfma(
    const AT* __restrict__ A,               // [M, K]
    const _Float16* __restrict__ WTf,       // [128][K] f16 (transposed W)
    const float* __restrict__ rowscale,     // [M]
    _Float16* __restrict__ C16,             // [M, 128] f16 out
    int M)
{
    constexpr int ASTR = 520;   // 64*8 + 8 ushort-equivalents (f16)
    constexpr int BSTR = 1032;  // 128*8 + 8
    __shared__ _Float16 Ah[4 * ASTR];
    __shared__ _Float16 Al[ATERMS == 2 ? 4 * ASTR : 8];
    __shared__ _Float16 Bf[4 * BSTR];

    const int tid = threadIdx.x;
    const int bm = blockIdx.x * 64;
    const int lane = tid & 63;
    const int wid = tid >> 6;
    const int wm = wid >> 1;         // 0..1: 32-row half
    const int wn = wid & 1;          // 0..1: 64-col half
    const int lr = lane & 15;
    const int lg = lane >> 4;

    const int st_ar = tid >> 2;      // A staging row 0..63
    const int st_s8 = tid & 3;       // A staging k-slot
    const int a_row_g = bm + st_ar;

    f32x4 acc[2][4];
    #pragma unroll
    for (int i = 0; i < 2; ++i)
        #pragma unroll
        for (int j = 0; j < 4; ++j)
            acc[i][j] = (f32x4){0.f, 0.f, 0.f, 0.f};

    float avreg[8];
    f16x8 areg16;
    f16x8 bv[2];

    auto load_tile = [&](int k0) {
        if (a_row_g < M) {
            const AT* ap = &A[(size_t)a_row_g * K + k0 + st_s8 * 8];
            if constexpr (sizeof(AT) == 4) {
                float4 v0 = *reinterpret_cast<const float4*>(ap);
                float4 v1 = *reinterpret_cast<const float4*>(ap + 4);
                avreg[0] = v0.x; avreg[1] = v0.y; avreg[2] = v0.z; avreg[3] = v0.w;
                avreg[4] = v1.x; avreg[5] = v1.y; avreg[6] = v1.z; avreg[7] = v1.w;
            } else {
                areg16 = *reinterpret_cast<const f16x8*>(ap);
            }
        } else {
            if constexpr (sizeof(AT) == 4) {
                #pragma unroll
                for (int j = 0; j < 8; ++j) avreg[j] = 0.f;
            } else {
                #pragma unroll
                for (int j = 0; j < 8; ++j) areg16[j] = (_Float16)0.f;
            }
        }
        #pragma unroll
        for (int i = 0; i < 2; ++i) {
            int lin = tid + i * 256;
            int col = lin >> 2;
            int s8  = lin & 3;
            bv[i] = *reinterpret_cast<const f16x8*>(&WTf[(size_t)col * K + k0 + s8 * 8]);
        }
    };

    load_tile(0);

    for (int k0 = 0; k0 < K; k0 += 32) {
        // ---- write LDS from regs ----
        {
            int off = st_s8 * ASTR + st_ar * 8;
            if constexpr (sizeof(AT) == 4) {
                f16x8 vh, vl;
                #pragma unroll
                for (int j = 0; j < 8; ++j) {
                    _Float16 h = (_Float16)avreg[j];
                    vh[j] = h;
                    vl[j] = (_Float16)(avreg[j] - (float)h);
                }
                *reinterpret_cast<f16x8*>(&Ah[off]) = vh;
                if constexpr (ATERMS == 2)
                    *reinterpret_cast<f16x8*>(&Al[off]) = vl;
            } else {
                *reinterpret_cast<f16x8*>(&Ah[off]) = areg16;
            }
            #pragma unroll
            for (int i = 0; i < 2; ++i) {
                int lin = tid + i * 256;
                int col = lin >> 2;
                int s8  = lin & 3;
                *reinterpret_cast<f16x8*>(&Bf[s8 * BSTR + col * 8]) = bv[i];
            }
        }
        __syncthreads();

        if (k0 + 32 < K) load_tile(k0 + 32);

        // ---- MFMA: one K=32 substep ----
        {
            f16x8 afh[2], afl[2], bf[4];
            #pragma unroll
            for (int mt = 0; mt < 2; ++mt) {
                int row = wm * 32 + mt * 16 + lr;
                int off = lg * ASTR + row * 8;
                afh[mt] = *reinterpret_cast<const f16x8*>(&Ah[off]);
                if constexpr (ATERMS == 2)
                    afl[mt] = *reinterpret_cast<const f16x8*>(&Al[off]);
            }
            #pragma unroll
            for (int nt = 0; nt < 4; ++nt) {
                int col = wn * 64 + nt * 16 + lr;
                bf[nt] = *reinterpret_cast<const f16x8*>(&Bf[lg * BSTR + col * 8]);
            }
            #pragma unroll
            for (int mt = 0; mt < 2; ++mt) {
                #pragma unroll
                for (int nt = 0; nt < 4; ++nt) {
                    acc[mt][nt] = __builtin_amdgcn_mfma_f32_16x16x32_f16(
                        afh[mt], bf[nt], acc[mt][nt], 0, 0, 0);
                    if constexpr (ATERMS == 2)
                        acc[mt][nt] = __builtin_amdgcn_mfma_f32_16x16x32_f16(
                            afl[mt], bf[nt], acc[mt][nt], 0, 0, 0);
                }
            }
        }
        __syncthreads();
    }

    #pragma unroll
    for (int mt = 0; mt < 2; ++mt) {
        #pragma unroll
        for (int r = 0; r < 4; ++r) {
            int row = bm + wm * 32 + mt * 16 + lg * 4 + r;
            if (row < M) {
                float s = rowscale[row];
                #pragma unroll
                for (int nt = 0; nt < 4; ++nt) {
                    int col = wn * 64 + nt * 16 + lr;
                    C16[(size_t)row * 128 + col] = (_Float16)(acc[mt][nt][r] * s);
                }
            }
        }
    }
}

// ---------------- CSR aggregation, both column halves in ONE dispatch ----
// 8 lanes per node, 8 cols each; 4-wide gather unroll. OT = f16 or f32 out.
template<typename OT>
__global__ __launch_bounds__(256) void aggregate_full(
    const _Float16* __restrict__ h16,
    const int* __restrict__ rowptr,
    const int* __restrict__ csr_src,
    const float* __restrict__ ndst,
    const float* __restrict__ bias,
    OT* __restrict__ out, int N, int half_blocks)
{
    int b = blockIdx.x;
    int c_base = 0;
    if (b >= half_blocks) { c_base = 64; b -= half_blocks; }
    int g = b * blockDim.x + threadIdx.x;
    int node = g >> 3;
    if (node >= N) return;
    int c8 = ((g & 7) * 8) + c_base;
    int beg = rowptr[node];
    int end = rowptr[node + 1];
    float acc[8] = {0.f, 0.f, 0.f, 0.f, 0.f, 0.f, 0.f, 0.f};
    int j = beg;
    for (; j + 3 < end; j += 4) {
        int s0 = csr_src[j];
        int s1 = csr_src[j + 1];
        int s2 = csr_src[j + 2];
        int s3 = csr_src[j + 3];
        f16x8 v0 = *reinterpret_cast<const f16x8*>(&h16[(size_t)s0 * 128 + c8]);
        f16x8 v1 = *reinterpret_cast<const f16x8*>(&h16[(size_t)s1 * 128 + c8]);
        f16x8 v2 = *reinterpret_cast<const f16x8*>(&h16[(size_t)s2 * 128 + c8]);
        f16x8 v3 = *reinterpret_cast<const f16x8*>(&h16[(size_t)s3 * 128 + c8]);
        #pragma unroll
        for (int k = 0; k < 8; ++k)
            acc[k] += ((float)v0[k] + (float)v1[k]) + ((float)v2[k] + (float)v3[k]);
    }
    for (; j < end; ++j) {
        int s0 = csr_src[j];
        f16x8 v0 = *reinterpret_cast<const f16x8*>(&h16[(size_t)s0 * 128 + c8]);
        #pragma unroll
        for (int k = 0; k < 8; ++k) acc[k] += (float)v0[k];
    }
    float sc = ndst[node];
    const float4 b0 = *reinterpret_cast<const float4*>(&bias[c8]);
    const float4 b1 = *reinterpret_cast<const float4*>(&bias[c8 + 4]);
    float r[8];
    r[0] = fmaxf(acc[0] * sc + b0.x, 0.f);
    r[1] = fmaxf(acc[1] * sc + b0.y, 0.f);
    r[2] = fmaxf(acc[2] * sc + b0.z, 0.f);
    r[3] = fmaxf(acc[3] * sc + b0.w, 0.f);
    r[4] = fmaxf(acc[4] * sc + b1.x, 0.f);
    r[5] = fmaxf(acc[5] * sc + b1.y, 0.f);
    r[6] = fmaxf(acc[6] * sc + b1.z, 0.f);
    r[7] = fmaxf(acc[7] * sc + b1.w, 0.f);
    OT* op = &out[(size_t)node * 128 + c8];
    if constexpr (sizeof(OT) == 4) {
        float4 r0 = {r[0], r[1], r[2], r[3]};
        float4 r1 = {r[4], r[5], r[6], r[7]};
        *reinterpret_cast<float4*>(op) = r0;
        *reinterpret_cast<float4*>(op + 4) = r1;
    } else {
        f16x8 rv;
        #pragma unroll
        for (int k = 0; k < 8; ++k) rv[k] = (_Float16)r[k];
        *reinterpret_cast<f16x8*>(op) = rv;
    }
}

extern "C" void kernel_launch(void* const* d_in, const int* in_sizes, int n_in,
                              void* d_out, int out_size, void* d_ws, size_t ws_size,
                              hipStream_t stream) {
    const float* feat = (const float*)d_in[0];   // [1, N, 256]
    const float* W1   = (const float*)d_in[1];   // [256, 128]
    const float* b1   = (const float*)d_in[2];   // [128]
    const float* W2   = (const float*)d_in[3];   // [128, 128]
    const float* b2   = (const float*)d_in[4];   // [128]
    const int* esrc   = (const int*)d_in[5];     // [E]
    const int* edst   = (const int*)d_in[6];     // [E]
    float* out = (float*)d_out;                  // [N, 128]

    const int Nn = N_NODES, E = N_EDGES;
    const int SCAN_N = 2 * MATP;                 // 200192
    const int SCAN_NB = (SCAN_N + 1023) / 1024;  // 196

    // workspace: h slot (N*128 f32-sized) holds h16 + h1out (both f16)
    float* hseg   = (float*)d_ws;
    _Float16* h16   = (_Float16*)hseg;
    _Float16* h1out = h16 + (size_t)Nn * 128;
    _Float16* WT1f = (_Float16*)(hseg + (size_t)Nn * 128);
    _Float16* WT2f = WT1f + 128 * 256;
    int* csr_src  = (int*)(WT2f + 128 * 128);
    int* rowptr   = csr_src + E;
    unsigned int* tmp = (unsigned int*)(rowptr + 100004);
    int* cnt_mat  = (int*)(tmp + 2 * (size_t)E);
    int* scan_mat = cnt_mat + SCAN_N;
    int* partials = scan_mat + SCAN_N;
    float* nsrc   = (float*)(partials + ((SCAN_NB + 3) & ~3));
    float* ndst   = nsrc + Nn;

    // --- setup: bucket histograms + weight transpose (f16) fused ---
    fused_setup<<<NBLK + 192, 256, 0, stream>>>(esrc, edst, cnt_mat, W1, WT1f, W2, WT2f);

    // --- scan ---
    scan_blocks<<<SCAN_NB, 1024, 0, stream>>>(cnt_mat, scan_mat, partials, SCAN_N);
    scan_partials<<<1, 256, 0, stream>>>(partials, SCAN_NB);

    // --- scatter + fused finalize ---
    bucket_scatter<<<NBLK, 256, 0, stream>>>(esrc, edst, scan_mat, partials, tmp);
    finalize_fused<<<2 * NBUCK, 256, 0, stream>>>(tmp, scan_mat, partials,
                                                  rowptr, csr_src, ndst, nsrc);

    const int gemm_grid = (Nn + 63) / 64;        // 1563
    const int aggh_grid = (Nn * 8 + 255) / 256;  // 3125

    // --- layer 1: gemm (A f32, 2-term) -> h16; aggregate -> h1out (f16) ---
    gemm_mfma<256, 2, float><<<gemm_grid, 256, 0, stream>>>(feat, WT1f, nsrc, h16, Nn);
    aggregate_full<_Float16><<<2 * aggh_grid, 256, 0, stream>>>(
        h16, rowptr, csr_src, ndst, b1, h1out, Nn, aggh_grid);

    // --- layer 2: gemm (A f16, 1-term) -> h16; aggregate -> d_out (f32) ---
    gemm_mfma<128, 1, _Float16><<<gemm_grid, 256, 0, stream>>>(h1out, WT2f, nsrc, h16, Nn);
    aggregate_full<float><<<2 * aggh_grid, 256, 0, stream>>>(
        h16, rowptr, csr_src, ndst, b2, out, Nn, aggh_grid);
}